// Round 1
// baseline (255.389 us; speedup 1.0000x reference)
//
#include <hip/hip_runtime.h>
#include <hip/hip_bf16.h>

// B=1024, N(nodes)=128, H=128, D=8
// out = [f_out (B*N)] ++ [g_out (B*N*D)], fp32
//
// Strategy: per node i, combined weight Wt_i[c][n] (c<1024: g cols h*8+d; c>=1024: f cols h),
// pre-transposed+bf16 in d_ws. Main kernel: x(128 rows)@Wt_i via mfma_f32_16x16x32_bf16,
// fused ELU + H-reduction epilogue in registers.

typedef unsigned short u16;
typedef __attribute__((ext_vector_type(8))) short bf16x8;
typedef __attribute__((ext_vector_type(4))) float f32x4;

typedef __attribute__((address_space(1))) const void* gas_ptr;
typedef __attribute__((address_space(3))) void* las_ptr;
#define GLOAD_LDS16(g, l) __builtin_amdgcn_global_load_lds((gas_ptr)(g), (las_ptr)(l), 16, 0, 0)

#define WS_W_ELEMS  ((size_t)128 * 1152 * 128)           // 18,874,368 u16
#define WS_X_ELEMS  ((size_t)1024 * 128)                 // 131,072 u16
#define WS_NEED_BYTES ((WS_W_ELEMS + WS_X_ELEMS) * 2)    // 38,010,880 B

__device__ __forceinline__ u16 f2bf(float f) {
    unsigned int u = __float_as_uint(f);
    u += 0x7fffu + ((u >> 16) & 1u);   // RNE
    return (u16)(u >> 16);
}
__device__ __forceinline__ float elu(float v) {
    return v > 0.f ? v : __expf(v) - 1.f;
}

// ---------- pre-pass: weights fp32 [i][n][C] -> bf16 ws [i][C][n] ----------
__global__ void sde_prepass_w(const float* __restrict__ fw, const float* __restrict__ gw,
                              u16* __restrict__ wsW) {
    __shared__ u16 tile[128 * 130];     // [cc][n], pad 130 -> conflict-free both phases
    const int t   = threadIdx.x;        // 256 threads
    const int blk = blockIdx.x;         // 1152 = 128 i * 9 chunks
    const int i   = blk / 9;
    const int ct  = blk % 9;            // ct<8: g chunk (128 cols), ct==8: f chunk
    const float* src;
    int sstride;
    if (ct < 8) { src = gw + (size_t)i * 131072 + ct * 128; sstride = 1024; }
    else        { src = fw + (size_t)i * 16384;             sstride = 128;  }
    // phase 1: coalesced read (n, cc), transposed LDS write
    const int cc = t & 127;
    for (int p = 0; p < 64; ++p) {
        int n = p * 2 + (t >> 7);
        tile[cc * 130 + n] = f2bf(src[(size_t)n * sstride + cc]);
    }
    __syncthreads();
    // phase 2: coalesced write of [C][n] rows (2 u16 per u32)
    const int n0 = (t & 63) * 2;
    uint32_t* dst32 = (uint32_t*)wsW;
    for (int p = 0; p < 32; ++p) {
        int c = p * 4 + (t >> 6);
        uint32_t v = *(const uint32_t*)&tile[c * 130 + n0];
        dst32[((size_t)i * 1152 + ct * 128 + c) * 64 + (t & 63)] = v;
    }
}

// ---------- pre-pass: x fp32 -> bf16 ----------
__global__ void sde_prepass_x(const float* __restrict__ x, u16* __restrict__ wsX) {
    const int tid = blockIdx.x * 256 + threadIdx.x;   // 32768 threads * float4
    float4 v = ((const float4*)x)[tid];
    uint32_t lo = (uint32_t)f2bf(v.x) | ((uint32_t)f2bf(v.y) << 16);
    uint32_t hi = (uint32_t)f2bf(v.z) | ((uint32_t)f2bf(v.w) << 16);
    ((uint2*)wsX)[tid] = make_uint2(lo, hi);
}

// ---------- main fused MFMA kernel ----------
// grid 1024 = 128 i * 8 btiles(128 rows), block 256 (4 waves, rows split 4x1)
__global__ __launch_bounds__(256) void sde_mfma(
    const u16* __restrict__ wsAll,
    const float* __restrict__ Wf, const float* __restrict__ bfp,
    const float* __restrict__ Wg, const float* __restrict__ bgp,
    float* __restrict__ out)
{
    __shared__ u16 xs[128 * 128];   // A tile [row][k], 32 KB
    __shared__ u16 wst[64 * 128];   // B tile [c][k], 16 KB
    __shared__ float wgs[128];
    __shared__ float wfs[128];

    const int t    = threadIdx.x;
    const int bx   = blockIdx.x;
    const int i    = bx >> 3;
    const int b0   = (bx & 7) << 7;
    const int w    = t >> 6;
    const int lane = t & 63;
    const int l15  = lane & 15;
    const int quad = lane >> 4;

    const u16* wsW = wsAll;
    const u16* wsX = wsAll + WS_W_ELEMS;

    if (t < 128) { wgs[t] = Wg[i * 128 + t]; wfs[t] = Wf[i * 128 + t]; }

    // stage x tile (identity copy, 32 KB, width-16 global->LDS)
    {
        const char* src = (const char*)(wsX + (size_t)b0 * 128);
        char* dst = (char*)xs;
        #pragma unroll
        for (int r = 0; r < 8; ++r) {
            int off = w * 8192 + r * 1024;
            GLOAD_LDS16(src + off + lane * 16, dst + off);
        }
    }

    float racc[8], frac[8];
    #pragma unroll
    for (int q = 0; q < 8; ++q) { racc[q] = 0.f; frac[q] = 0.f; }

    for (int ct = 0; ct < 18; ++ct) {
        // stage 64-col weight tile (16 KB contiguous)
        {
            const char* srcW = (const char*)(wsW + ((size_t)i * 1152 + ct * 64) * 128);
            char* dstW = (char*)wst;
            #pragma unroll
            for (int r = 0; r < 4; ++r) {
                int off = w * 4096 + r * 1024;
                GLOAD_LDS16(srcW + off + lane * 16, dstW + off);
            }
        }
        __syncthreads();

        f32x4 acc[2][4];
        #pragma unroll
        for (int rs = 0; rs < 2; ++rs)
            #pragma unroll
            for (int cs = 0; cs < 4; ++cs)
                acc[rs][cs] = (f32x4){0.f, 0.f, 0.f, 0.f};

        #pragma unroll
        for (int kk = 0; kk < 4; ++kk) {
            const int kb = kk * 32 + quad * 8;
            bf16x8 a0 = *(const bf16x8*)&xs[(w * 32 + l15) * 128 + kb];
            bf16x8 a1 = *(const bf16x8*)&xs[(w * 32 + 16 + l15) * 128 + kb];
            bf16x8 bv[4];
            #pragma unroll
            for (int cs = 0; cs < 4; ++cs)
                bv[cs] = *(const bf16x8*)&wst[(cs * 16 + l15) * 128 + kb];
            #pragma unroll
            for (int cs = 0; cs < 4; ++cs) {
                acc[0][cs] = __builtin_amdgcn_mfma_f32_16x16x32_bf16(a0, bv[cs], acc[0][cs], 0, 0, 0);
                acc[1][cs] = __builtin_amdgcn_mfma_f32_16x16x32_bf16(a1, bv[cs], acc[1][cs], 0, 0, 0);
            }
        }

        // fused epilogue: C/D layout col=l15, row=quad*4+reg
        if (ct < 16) {
            // g cols: C = ct*64 + cs*16 + l15 = h*8+d ; d = l15&7, h = ct*8 + cs*2 + (l15>>3)
            float wv[4];
            #pragma unroll
            for (int cs = 0; cs < 4; ++cs) wv[cs] = wgs[ct * 8 + cs * 2 + (l15 >> 3)];
            #pragma unroll
            for (int rs = 0; rs < 2; ++rs)
                #pragma unroll
                for (int rg = 0; rg < 4; ++rg) {
                    float p = elu(acc[rs][0][rg]) * wv[0] + elu(acc[rs][1][rg]) * wv[1]
                            + elu(acc[rs][2][rg]) * wv[2] + elu(acc[rs][3][rg]) * wv[3];
                    p += __shfl_xor(p, 8);     // partner lane covers complementary h set
                    racc[rs * 4 + rg] += p;
                }
        } else {
            // f cols: h = (ct-16)*64 + cs*16 + l15 ; full 16-lane row reduction
            float wv[4];
            #pragma unroll
            for (int cs = 0; cs < 4; ++cs) wv[cs] = wfs[(ct - 16) * 64 + cs * 16 + l15];
            #pragma unroll
            for (int rs = 0; rs < 2; ++rs)
                #pragma unroll
                for (int rg = 0; rg < 4; ++rg) {
                    float p = elu(acc[rs][0][rg]) * wv[0] + elu(acc[rs][1][rg]) * wv[1]
                            + elu(acc[rs][2][rg]) * wv[2] + elu(acc[rs][3][rg]) * wv[3];
                    p += __shfl_xor(p, 1);
                    p += __shfl_xor(p, 2);
                    p += __shfl_xor(p, 4);
                    p += __shfl_xor(p, 8);
                    frac[rs * 4 + rg] += p;
                }
        }
        __syncthreads();   // wst safe to overwrite next iter
    }

    // writeout (each (row,d) held by lanes l15 and l15^8; rows unique per wave)
    const float bfv = bfp[i], bgv = bgp[i];
    #pragma unroll
    for (int rs = 0; rs < 2; ++rs)
        #pragma unroll
        for (int rg = 0; rg < 4; ++rg) {
            int row = w * 32 + rs * 16 + quad * 4 + rg;
            size_t brow = (size_t)(b0 + row);
            if (l15 == 0)
                out[brow * 128 + i] = frac[rs * 4 + rg] + bfv;
            if (l15 < 8)
                out[(size_t)131072 + (brow * 128 + i) * 8 + (lane & 7)] = racc[rs * 4 + rg] + bgv;
        }
}

// ---------- fp32 fallback (only if ws too small) ----------
__global__ void sde_fallback(const float* __restrict__ x, const float* __restrict__ fw,
                             const float* __restrict__ gw,
                             const float* __restrict__ Wf, const float* __restrict__ bfp,
                             const float* __restrict__ Wg, const float* __restrict__ bgp,
                             float* __restrict__ out)
{
    __shared__ float xsh[64 * 128];
    const int t  = threadIdx.x;           // 64
    const int i  = blockIdx.x >> 4;
    const int b0 = (blockIdx.x & 15) << 6;
    for (int idx = t; idx < 64 * 128; idx += 64) xsh[idx] = x[(size_t)b0 * 128 + idx];
    __syncthreads();
    const float* xr  = &xsh[t * 128];
    const float* fwi = fw + (size_t)i * 16384;
    const float* gwi = gw + (size_t)i * 131072;
    float fa = 0.f;
    for (int h = 0; h < 128; ++h) {
        float tf = 0.f;
        for (int n = 0; n < 128; ++n) tf += xr[n] * fwi[n * 128 + h];
        fa += elu(tf) * Wf[i * 128 + h];
    }
    float ga[8];
    #pragma unroll
    for (int d = 0; d < 8; ++d) ga[d] = 0.f;
    for (int h = 0; h < 128; ++h) {
        float tg[8] = {0, 0, 0, 0, 0, 0, 0, 0};
        for (int n = 0; n < 128; ++n) {
            float xv = xr[n];
            const float* gp = gwi + ((size_t)n * 128 + h) * 8;
            #pragma unroll
            for (int d = 0; d < 8; ++d) tg[d] += xv * gp[d];
        }
        float wv = Wg[i * 128 + h];
        #pragma unroll
        for (int d = 0; d < 8; ++d) ga[d] += elu(tg[d]) * wv;
    }
    size_t b = (size_t)(b0 + t);
    out[b * 128 + i] = fa + bfp[i];
    #pragma unroll
    for (int d = 0; d < 8; ++d)
        out[(size_t)131072 + (b * 128 + i) * 8 + d] = ga[d] + bgp[i];
}

extern "C" void kernel_launch(void* const* d_in, const int* in_sizes, int n_in,
                              void* d_out, int out_size, void* d_ws, size_t ws_size,
                              hipStream_t stream) {
    const float* x  = (const float*)d_in[0];
    const float* fw = (const float*)d_in[1];
    const float* gw = (const float*)d_in[2];
    const float* Wf = (const float*)d_in[3];
    const float* bf = (const float*)d_in[4];
    const float* Wg = (const float*)d_in[5];
    const float* bg = (const float*)d_in[6];
    float* out = (float*)d_out;

    if (ws_size >= WS_NEED_BYTES) {
        u16* wsAll = (u16*)d_ws;
        sde_prepass_w<<<1152, 256, 0, stream>>>(fw, gw, wsAll);
        sde_prepass_x<<<128, 256, 0, stream>>>(x, wsAll + WS_W_ELEMS);
        sde_mfma<<<1024, 256, 0, stream>>>(wsAll, Wf, bf, Wg, bg, out);
    } else {
        sde_fallback<<<2048, 64, 0, stream>>>(x, fw, gw, Wf, bf, Wg, bg, out);
    }
}

// Round 2
// 185.011 us; speedup vs baseline: 1.3804x; 1.3804x over previous
//
#include <hip/hip_runtime.h>
#include <hip/hip_bf16.h>

// B=1024, N(nodes)=128, H=128, D=8
// out = [f_out (B*N)] ++ [g_out (B*N*D)], fp32
//
// Per node i, combined weight Wt_i[c][n] (c<1024: g cols h*8+d; c>=1024: f cols h),
// pre-transposed+bf16 in d_ws. Main kernel: x(128 rows)@Wt_i via mfma_f32_16x16x32_bf16,
// fused ELU + H-reduction epilogue in registers.
//
// R2: XOR-swizzled LDS chunk layout (via per-lane global_load_lds source addresses)
// to kill the 16-way bank conflicts of 256B-stride rows; XCD-aware block swizzle
// (same-node blocks share an XCD's L2); vectorized prepass_w.

typedef unsigned short u16;
typedef __attribute__((ext_vector_type(8))) short bf16x8;
typedef __attribute__((ext_vector_type(4))) float f32x4;

typedef __attribute__((address_space(1))) const void* gas_ptr;
typedef __attribute__((address_space(3))) void* las_ptr;
#define GLOAD_LDS16(g, l) __builtin_amdgcn_global_load_lds((gas_ptr)(g), (las_ptr)(l), 16, 0, 0)

#define WS_W_ELEMS  ((size_t)128 * 1152 * 128)           // 18,874,368 u16
#define WS_X_ELEMS  ((size_t)1024 * 128)                 // 131,072 u16
#define WS_NEED_BYTES ((WS_W_ELEMS + WS_X_ELEMS) * 2)    // 38,010,880 B

__device__ __forceinline__ u16 f2bf(float f) {
    unsigned int u = __float_as_uint(f);
    u += 0x7fffu + ((u >> 16) & 1u);   // RNE
    return (u16)(u >> 16);
}
__device__ __forceinline__ uint32_t pack2bf(float a, float b) {
    return (uint32_t)f2bf(a) | ((uint32_t)f2bf(b) << 16);
}
__device__ __forceinline__ float elu(float v) {
    return v > 0.f ? v : __expf(v) - 1.f;
}

// ---------- pre-pass: weights fp32 [i][n][C] -> bf16 ws [i][C][n] ----------
__global__ void sde_prepass_w(const float* __restrict__ fw, const float* __restrict__ gw,
                              u16* __restrict__ wsW) {
    __shared__ u16 tile[128 * 130];     // [cc][n], pad 130
    const int t   = threadIdx.x;        // 256 threads
    const int blk = blockIdx.x;         // 1152 = 128 i * 9 chunks
    const int i   = blk / 9;
    const int ct  = blk % 9;            // ct<8: g chunk (128 cols), ct==8: f chunk
    const float* src;
    int sstride;
    if (ct < 8) { src = gw + (size_t)i * 131072 + ct * 128; sstride = 1024; }
    else        { src = fw + (size_t)i * 16384;             sstride = 128;  }
    // phase 1: float4 reads (rows n, n+1), packed u32 transposed LDS writes
    const int c4 = (t & 31) * 4;        // column group
    const int np = (t >> 5) * 2;        // row pair base
    for (int p = 0; p < 8; ++p) {
        int n = p * 16 + np;
        float4 v0 = *(const float4*)&src[(size_t)n * sstride + c4];
        float4 v1 = *(const float4*)&src[(size_t)(n + 1) * sstride + c4];
        *(uint32_t*)&tile[(c4 + 0) * 130 + n] = pack2bf(v0.x, v1.x);
        *(uint32_t*)&tile[(c4 + 1) * 130 + n] = pack2bf(v0.y, v1.y);
        *(uint32_t*)&tile[(c4 + 2) * 130 + n] = pack2bf(v0.z, v1.z);
        *(uint32_t*)&tile[(c4 + 3) * 130 + n] = pack2bf(v0.w, v1.w);
    }
    __syncthreads();
    // phase 2: coalesced write of [C][n] rows (2 u16 per u32)
    const int n0 = (t & 63) * 2;
    uint32_t* dst32 = (uint32_t*)wsW;
    for (int p = 0; p < 32; ++p) {
        int c = p * 4 + (t >> 6);
        uint32_t v = *(const uint32_t*)&tile[c * 130 + n0];
        dst32[((size_t)i * 1152 + ct * 128 + c) * 64 + (t & 63)] = v;
    }
}

// ---------- pre-pass: x fp32 -> bf16 ----------
__global__ void sde_prepass_x(const float* __restrict__ x, u16* __restrict__ wsX) {
    const int tid = blockIdx.x * 256 + threadIdx.x;   // 32768 threads * float4
    float4 v = ((const float4*)x)[tid];
    ((uint2*)wsX)[tid] = make_uint2(pack2bf(v.x, v.y), pack2bf(v.z, v.w));
}

// ---------- main fused MFMA kernel ----------
// grid 1024; bx&127 = node i (same-node blocks share XCD), bx>>7 = btile (128 rows)
// block 256 (4 waves, rows split 4x1)
__global__ __launch_bounds__(256) void sde_mfma(
    const u16* __restrict__ wsAll,
    const float* __restrict__ Wf, const float* __restrict__ bfp,
    const float* __restrict__ Wg, const float* __restrict__ bgp,
    float* __restrict__ out)
{
    // Swizzled layout: LDS[row][chunk j] (16B chunks, 16/row) holds global chunk j^(row&7).
    __shared__ u16 xs[128 * 128];   // A tile, 32 KB
    __shared__ u16 wst[64 * 128];   // B tile, 16 KB
    __shared__ float wgs[128];
    __shared__ float wfs[128];

    const int t    = threadIdx.x;
    const int bx   = blockIdx.x;
    const int i    = bx & 127;      // XCD-affine: all 8 blocks of node i have bx%8 == i%8
    const int b0   = (bx >> 7) << 7;
    const int w    = t >> 6;
    const int lane = t & 63;
    const int l15  = lane & 15;
    const int quad = lane >> 4;
    const int rl   = lane >> 4;     // row-in-group for staging
    const int j16  = lane & 15;     // chunk for staging
    const int sw   = l15 & 7;       // read-side swizzle (row&7 == l15&7 for all our rows)

    const u16* wsW = wsAll;
    const u16* wsX = wsAll + WS_W_ELEMS;

    if (t < 128) { wgs[t] = Wg[i * 128 + t]; wfs[t] = Wf[i * 128 + t]; }

    // stage x tile (32 KB, swizzled via per-lane source chunk)
    {
        const char* srcX = (const char*)(wsX + (size_t)b0 * 128);
        #pragma unroll
        for (int r = 0; r < 8; ++r) {
            int row = w * 32 + r * 4 + rl;
            int soff = row * 256 + ((j16 ^ (row & 7)) << 4);
            GLOAD_LDS16(srcX + soff, (char*)xs + w * 8192 + r * 1024);
        }
    }

    float racc[8], frac[8];
    #pragma unroll
    for (int q = 0; q < 8; ++q) { racc[q] = 0.f; frac[q] = 0.f; }

    for (int ct = 0; ct < 18; ++ct) {
        // stage 64-col weight tile (16 KB, swizzled)
        {
            const char* srcW = (const char*)(wsW + ((size_t)i * 1152 + ct * 64) * 128);
            #pragma unroll
            for (int r = 0; r < 4; ++r) {
                int row = w * 16 + r * 4 + rl;
                int soff = row * 256 + ((j16 ^ (row & 7)) << 4);
                GLOAD_LDS16(srcW + soff, (char*)wst + w * 4096 + r * 1024);
            }
        }
        __syncthreads();

        f32x4 acc[2][4];
        #pragma unroll
        for (int rs = 0; rs < 2; ++rs)
            #pragma unroll
            for (int cs = 0; cs < 4; ++cs)
                acc[rs][cs] = (f32x4){0.f, 0.f, 0.f, 0.f};

        const int r0 = w * 32 + l15;
        #pragma unroll
        for (int kk = 0; kk < 4; ++kk) {
            const int co = ((kk * 4 + quad) ^ sw) << 3;   // swizzled u16 offset in row
            bf16x8 a0 = *(const bf16x8*)&xs[r0 * 128 + co];
            bf16x8 a1 = *(const bf16x8*)&xs[(r0 + 16) * 128 + co];
            bf16x8 bv[4];
            #pragma unroll
            for (int cs = 0; cs < 4; ++cs)
                bv[cs] = *(const bf16x8*)&wst[(cs * 16 + l15) * 128 + co];
            #pragma unroll
            for (int cs = 0; cs < 4; ++cs) {
                acc[0][cs] = __builtin_amdgcn_mfma_f32_16x16x32_bf16(a0, bv[cs], acc[0][cs], 0, 0, 0);
                acc[1][cs] = __builtin_amdgcn_mfma_f32_16x16x32_bf16(a1, bv[cs], acc[1][cs], 0, 0, 0);
            }
        }

        // fused epilogue: C/D layout col=l15, row=quad*4+reg
        if (ct < 16) {
            // g cols: C = ct*64 + cs*16 + l15 = h*8+d ; d = l15&7, h = ct*8 + cs*2 + (l15>>3)
            float wv[4];
            #pragma unroll
            for (int cs = 0; cs < 4; ++cs) wv[cs] = wgs[ct * 8 + cs * 2 + (l15 >> 3)];
            #pragma unroll
            for (int rs = 0; rs < 2; ++rs)
                #pragma unroll
                for (int rg = 0; rg < 4; ++rg) {
                    float p = elu(acc[rs][0][rg]) * wv[0] + elu(acc[rs][1][rg]) * wv[1]
                            + elu(acc[rs][2][rg]) * wv[2] + elu(acc[rs][3][rg]) * wv[3];
                    p += __shfl_xor(p, 8);     // partner lane covers complementary h set
                    racc[rs * 4 + rg] += p;
                }
        } else {
            // f cols: h = (ct-16)*64 + cs*16 + l15 ; full 16-lane row reduction
            float wv[4];
            #pragma unroll
            for (int cs = 0; cs < 4; ++cs) wv[cs] = wfs[(ct - 16) * 64 + cs * 16 + l15];
            #pragma unroll
            for (int rs = 0; rs < 2; ++rs)
                #pragma unroll
                for (int rg = 0; rg < 4; ++rg) {
                    float p = elu(acc[rs][0][rg]) * wv[0] + elu(acc[rs][1][rg]) * wv[1]
                            + elu(acc[rs][2][rg]) * wv[2] + elu(acc[rs][3][rg]) * wv[3];
                    p += __shfl_xor(p, 1);
                    p += __shfl_xor(p, 2);
                    p += __shfl_xor(p, 4);
                    p += __shfl_xor(p, 8);
                    frac[rs * 4 + rg] += p;
                }
        }
        __syncthreads();   // wst safe to overwrite next iter
    }

    // writeout (each (row,d) held by lanes l15 and l15^8; rows unique per wave)
    const float bfv = bfp[i], bgv = bgp[i];
    #pragma unroll
    for (int rs = 0; rs < 2; ++rs)
        #pragma unroll
        for (int rg = 0; rg < 4; ++rg) {
            int row = w * 32 + rs * 16 + quad * 4 + rg;
            size_t brow = (size_t)(b0 + row);
            if (l15 == 0)
                out[brow * 128 + i] = frac[rs * 4 + rg] + bfv;
            if (l15 < 8)
                out[(size_t)131072 + (brow * 128 + i) * 8 + (lane & 7)] = racc[rs * 4 + rg] + bgv;
        }
}

// ---------- fp32 fallback (only if ws too small) ----------
__global__ void sde_fallback(const float* __restrict__ x, const float* __restrict__ fw,
                             const float* __restrict__ gw,
                             const float* __restrict__ Wf, const float* __restrict__ bfp,
                             const float* __restrict__ Wg, const float* __restrict__ bgp,
                             float* __restrict__ out)
{
    __shared__ float xsh[64 * 128];
    const int t  = threadIdx.x;           // 64
    const int i  = blockIdx.x >> 4;
    const int b0 = (blockIdx.x & 15) << 6;
    for (int idx = t; idx < 64 * 128; idx += 64) xsh[idx] = x[(size_t)b0 * 128 + idx];
    __syncthreads();
    const float* xr  = &xsh[t * 128];
    const float* fwi = fw + (size_t)i * 16384;
    const float* gwi = gw + (size_t)i * 131072;
    float fa = 0.f;
    for (int h = 0; h < 128; ++h) {
        float tf = 0.f;
        for (int n = 0; n < 128; ++n) tf += xr[n] * fwi[n * 128 + h];
        fa += elu(tf) * Wf[i * 128 + h];
    }
    float ga[8];
    #pragma unroll
    for (int d = 0; d < 8; ++d) ga[d] = 0.f;
    for (int h = 0; h < 128; ++h) {
        float tg[8] = {0, 0, 0, 0, 0, 0, 0, 0};
        for (int n = 0; n < 128; ++n) {
            float xv = xr[n];
            const float* gp = gwi + ((size_t)n * 128 + h) * 8;
            #pragma unroll
            for (int d = 0; d < 8; ++d) tg[d] += xv * gp[d];
        }
        float wv = Wg[i * 128 + h];
        #pragma unroll
        for (int d = 0; d < 8; ++d) ga[d] += elu(tg[d]) * wv;
    }
    size_t b = (size_t)(b0 + t);
    out[b * 128 + i] = fa + bfp[i];
    #pragma unroll
    for (int d = 0; d < 8; ++d)
        out[(size_t)131072 + (b * 128 + i) * 8 + d] = ga[d] + bgp[i];
}

extern "C" void kernel_launch(void* const* d_in, const int* in_sizes, int n_in,
                              void* d_out, int out_size, void* d_ws, size_t ws_size,
                              hipStream_t stream) {
    const float* x  = (const float*)d_in[0];
    const float* fw = (const float*)d_in[1];
    const float* gw = (const float*)d_in[2];
    const float* Wf = (const float*)d_in[3];
    const float* bf = (const float*)d_in[4];
    const float* Wg = (const float*)d_in[5];
    const float* bg = (const float*)d_in[6];
    float* out = (float*)d_out;

    if (ws_size >= WS_NEED_BYTES) {
        u16* wsAll = (u16*)d_ws;
        sde_prepass_w<<<1152, 256, 0, stream>>>(fw, gw, wsAll);
        sde_prepass_x<<<128, 256, 0, stream>>>(x, wsAll + WS_W_ELEMS);
        sde_mfma<<<1024, 256, 0, stream>>>(wsAll, Wf, bf, Wg, bg, out);
    } else {
        sde_fallback<<<2048, 64, 0, stream>>>(x, fw, gw, Wf, bf, Wg, bg, out);
    }
}